// Round 1
// baseline (192.756 us; speedup 1.0000x reference)
//
#include <hip/hip_runtime.h>

typedef unsigned int u32;
typedef unsigned short u16;
typedef unsigned char u8;
typedef __attribute__((ext_vector_type(8))) __bf16 bf16x8;
typedef __attribute__((ext_vector_type(4))) float f32x4;

#define NB 16384
#define NM 4096
#define ND 512
#define NOUT 128
#define L2E 1.44269504088896340736f

// ws layout: x_ws fp8 [rb(256)][kg64(64)][row(64)][8B]   (8 MB)
//            s_ws fp8 [mb(32)][kg64(64)][m(128)][8B]     (2 MB, pre-scaled by -2*gamma*log2e)
//            hw_ws bf16 [slab=(mb*16+kg)][o(128)][8]     (1 MB)
// x2g[16384] = gamma*log2e*||x||^2 ; s2g[4096] = gamma*log2e*||s||^2  (fp32-exact)

// counted-vmcnt wait + scheduling fence (rule #18: sched_barrier after asm wait)
#define WAITVM(N) do { asm volatile("s_waitcnt vmcnt(" #N ")" ::: "memory"); \
                       __builtin_amdgcn_sched_barrier(0); } while (0)

// ---------- helpers ----------
__device__ __forceinline__ u16 f2bf(float f) {
  u32 u = __float_as_uint(f);
  u += 0x7FFFu + ((u >> 16) & 1u);   // RNE
  return (u16)(u >> 16);
}

// manual fp32 -> e4m3fn (RNE, flush |v|<2^-6 to 0; |v| <= ~15 here so no sat needed)
__device__ __forceinline__ u8 f2fp8(float f) {
  u32 u = __float_as_uint(f);
  u32 s = (u >> 24) & 0x80u;
  u32 au = u & 0x7FFFFFFFu;
  if (au < 0x3C800000u) return (u8)s;          // below min normal -> 0
  au += 0x000FFFFFu + ((au >> 20) & 1u);       // RNE to 3 mantissa bits
  u32 e = (au >> 23) - 120u;                   // rebias 127 -> 7
  u32 m = (au >> 20) & 7u;
  return (u8)(s | (e << 3) | m);
}

__device__ __forceinline__ void stage16(const void* g, void* l) {
  __builtin_amdgcn_global_load_lds((__attribute__((address_space(1))) void*)g,
                                   (__attribute__((address_space(3))) void*)l,
                                   16, 0, 0);
}

__device__ __forceinline__ uint4 pack8bf(float4 v0, float4 v1) {
  uint4 pk;
  pk.x = (u32)f2bf(v0.x) | ((u32)f2bf(v0.y) << 16);
  pk.y = (u32)f2bf(v0.z) | ((u32)f2bf(v0.w) << 16);
  pk.z = (u32)f2bf(v1.x) | ((u32)f2bf(v1.y) << 16);
  pk.w = (u32)f2bf(v1.z) | ((u32)f2bf(v1.w) << 16);
  return pk;
}

__device__ __forceinline__ uint2 pack8f8(float4 v0, float4 v1) {
  uint2 pk;
  pk.x = (u32)f2fp8(v0.x) | ((u32)f2fp8(v0.y) << 8) |
         ((u32)f2fp8(v0.z) << 16) | ((u32)f2fp8(v0.w) << 24);
  pk.y = (u32)f2fp8(v1.x) | ((u32)f2fp8(v1.y) << 8) |
         ((u32)f2fp8(v1.z) << 16) | ((u32)f2fp8(v1.w) << 24);
  return pk;
}

// ---------- merged prep ----------
// blocks [0,512): x tiles (fp8)   [512,640): support tiles (fp8, scaled)
// [640,672): head_w (bf16)        [672,736): zero d_out (64 blocks x 128 KB — was 16x512KB tail)
__global__ __launch_bounds__(256) void prep_all(const float* __restrict__ x,
                                                const float* __restrict__ s,
                                                const float* __restrict__ hw,
                                                const float* __restrict__ gamma_p,
                                                u8*  __restrict__ x_ws,
                                                u8*  __restrict__ s_ws,
                                                u16* __restrict__ hw_ws,
                                                float* __restrict__ x2g,
                                                float* __restrict__ s2g,
                                                float* __restrict__ out) {
  __shared__ uint2 t8[2048];       // 16 KB (x/s transpose, XOR-swizzled)
  __shared__ uint4 t16[2048];      // 32 KB (hw transpose)
  const int tid = threadIdx.x, bid = blockIdx.x;
  const int lane = tid & 63, w = tid >> 6;

  if (bid < 640) {
    const bool isx = bid < 512;
    const int blk = isx ? bid : (bid - 512);
    const float* src_m = isx ? x : s;
    u8*    dst_ws = isx ? x_ws : s_ws;
    float* sq_out = isx ? x2g : s2g;
    const float gl   = gamma_p[0] * L2E;
    const float cmul = isx ? 1.0f : (-2.0f * gl);
    const int big  = isx ? (blk >> 1) : (blk >> 2);
    const int roff = isx ? ((blk & 1) * 32) : ((blk & 3) * 32);
    const int rows = isx ? 64 : 128;

    #pragma unroll
    for (int p = 0; p < 8; ++p) {
      const int row = p * 4 + w;                      // local row 0..31
      const float* src = src_m + (size_t)(blk * 32 + row) * ND + lane * 8;
      float4 v0 = *(const float4*)src;
      float4 v1 = *(const float4*)(src + 4);
      float ss = v0.x*v0.x + v0.y*v0.y + v0.z*v0.z + v0.w*v0.w
               + v1.x*v1.x + v1.y*v1.y + v1.z*v1.z + v1.w*v1.w;
      #pragma unroll
      for (int off = 32; off > 0; off >>= 1) ss += __shfl_down(ss, off);
      if (lane == 0) sq_out[blk * 32 + row] = gl * ss;
      v0.x *= cmul; v0.y *= cmul; v0.z *= cmul; v0.w *= cmul;
      v1.x *= cmul; v1.y *= cmul; v1.z *= cmul; v1.w *= cmul;
      t8[lane * 32 + ((row + lane) & 31)] = pack8f8(v0, v1);   // kg = lane
    }
    __syncthreads();
    #pragma unroll
    for (int p = 0; p < 8; ++p) {
      const int kg = p * 8 + (tid >> 5);
      const int row = tid & 31;
      uint2 pk = t8[kg * 32 + ((row + kg) & 31)];
      *(uint2*)&dst_ws[(((size_t)(big * 64 + kg)) * rows + roff + row) * 8] = pk;
    }
  } else if (bid < 672) {
    // ---- head_w: m-chunk of 128 (bf16) ----
    const int blk = bid - 640;
    #pragma unroll
    for (int p = 0; p < 8; ++p) {
      const int o = p * 16 + (tid >> 4);
      const int kg = tid & 15;
      const float* src = hw + (size_t)o * NM + blk * 128 + kg * 8;
      float4 v0 = *(const float4*)src;
      float4 v1 = *(const float4*)(src + 4);
      t16[o * 16 + ((kg + o) & 15)] = pack8bf(v0, v1);
    }
    __syncthreads();
    #pragma unroll
    for (int it = 0; it < 8; ++it) {
      const int kg = it * 2 + (tid >> 7);
      const int o = tid & 127;
      uint4 pk = t16[o * 16 + ((kg + o) & 15)];
      *(uint4*)&hw_ws[(((size_t)(blk * 16 + kg)) * 128 + o) * 8] = pk;
    }
  } else {
    // ---- zero d_out: 64 blocks x 128 KB (spread the write tail over 64 CUs) ----
    float4* o4 = (float4*)out;
    const float4 z = {0.f, 0.f, 0.f, 0.f};
    size_t base = (size_t)(bid - 672) * 8192 + tid;
    #pragma unroll 8
    for (int i = 0; i < 32; ++i) o4[base + (size_t)i * 256] = z;
  }
}

// ---------- main fused kernel ----------
// grid 1024: xcd = bid&7, half = xcd>>1 (M quarter), rb = (bid>>3)*2 + (xcd&1) (256 blocks of 64 rows).
// block 256 = 4 waves; wave tile 32x64 (2x4 16x16x32 fp8 mfma frags for GEMM1, bf16 for GEMM2).
// LDS 64 KB: X fp8 32 KB @0 (LDS-resident whole kernel); Sbuf[2] 8 KB ea @32768; Ks bf16 16 KB @49152.
// launch_bounds (256,2) is load-bearing (R2: ",4" spills accs 6x; R4: no bound -> 1 wave/SIMD).
//
// R-new: counted-vmcnt 2-barrier schedule (T3/T4). Per grp:
//   [barrier_A (grp>0)] [b2 preload (even)] [stage(grp+1)] [s_waitcnt vmcnt(K)] [barrier_B]
//   [compute_kc x2] [gemm2 mma (even, mt>0)]
// K = #vmem ops younger than stage(grp): grp0: s2v(4)+b2(4)+stage(2)=10; even: b2+stage=6;
// odd: stage=2; (7,7): 0.  Raw s_barriers (no compiler vmcnt(0) drain); b2 loaded BEFORE the
// stage so its compiler wait (vmcnt(2)) leaves the prefetch in flight; epilogue barrier is
// lgkmcnt(0)-only so stage(mt+1,0) survives across the mtile boundary.
__global__ __launch_bounds__(256, 2)
void rbf_fused(const u8* __restrict__ x_ws, const u8* __restrict__ s_ws,
               const u16* __restrict__ hw_ws, const float* __restrict__ x2g,
               const float* __restrict__ s2g, const float* __restrict__ head_b,
               const float* __restrict__ scale_p, const float* __restrict__ shift_p,
               float* __restrict__ out)
{
  __shared__ __align__(16) char smem[65536];   // 64 KB

  const int tid  = threadIdx.x;
  const int w    = tid >> 6;
  const int lane = tid & 63;
  const int quad = lane >> 4;
  const int l16  = lane & 15;
  const int wr   = w & 1;    // row half (32 rows)
  const int wc   = w >> 1;   // m / out-col half (64)
  const int xcd  = blockIdx.x & 7;
  const int rb   = (blockIdx.x >> 3) * 2 + (xcd & 1);
  const int half = xcd >> 1;
  const int b0   = rb * 64;

  const float vscale = scale_p[0];
  const float vshift = shift_p[0];

  const u8* xsrc = x_ws + (size_t)rb * 32768;
  const u8* ssrc = s_ws + (size_t)(half * 8) * 65536;

  // ---- stage the whole X slice (32 KB) once ----
  #pragma unroll
  for (int i = 0; i < 8; ++i)
    stage16(xsrc + i * 4096 + tid * 16, smem + i * 4096 + tid * 16);

  f32x4 x2v[2];
  #pragma unroll
  for (int r = 0; r < 2; ++r)
    x2v[r] = *(const f32x4*)&x2g[b0 + wr * 32 + r * 16 + quad * 4];

  const f32x4 zf = {0.f, 0.f, 0.f, 0.f};
  f32x4 acc_xs[2][4];
  f32x4 acc_out[2][4];
  #pragma unroll
  for (int r = 0; r < 2; ++r)
    #pragma unroll
    for (int c = 0; c < 4; ++c) { acc_xs[r][c] = zf; acc_out[r][c] = zf; }

  auto stage_sgrp = [&](int mt, int grp, int buf) {
    const u8* sp = ssrc + (size_t)mt * 65536 + grp * 8192;
    char* dp = smem + 32768 + buf * 8192;
    stage16(sp + tid * 16, dp + tid * 16);
    stage16(sp + 4096 + tid * 16, dp + 4096 + tid * 16);
  };

  // one kc (K=32): 2 A-frags (X resident) x 4 B-frags (Sbuf) -> 8 fp8 MFMA
  auto compute_kc = [&](int kc, int kcL, int buf) {
    long long a[2], b[4];
    #pragma unroll
    for (int r = 0; r < 2; ++r)
      a[r] = *(const long long*)(smem + ((kc * 4 + quad) * 64 + wr * 32 + r * 16 + l16) * 8);
    #pragma unroll
    for (int c = 0; c < 4; ++c)
      b[c] = *(const long long*)(smem + 32768 + buf * 8192 +
                                 ((kcL * 4 + quad) * 128 + wc * 64 + c * 16 + l16) * 8);
    #pragma unroll
    for (int r = 0; r < 2; ++r)
      #pragma unroll
      for (int c = 0; c < 4; ++c)
        acc_xs[r][c] = __builtin_amdgcn_mfma_f32_16x16x32_fp8_fp8(a[r], b[c], acc_xs[r][c], 0, 0, 0);
  };

  // GEMM2 B-operand loads (4 x global_load_dwordx4 = 4 vmcnt events)
  auto g2_load = [&](int mtg2, int ks, bf16x8* b2) {
    const int kg = ks * 4 + quad;
    const size_t slab = (size_t)(mtg2 * 16 + kg);
    #pragma unroll
    for (int c = 0; c < 4; ++c)
      b2[c] = *(const bf16x8*)(hw_ws + (slab * 128 + wc * 64 + c * 16 + l16) * 8);
  };

  // GEMM2 MFMAs: acc_out += Ks-slice * preloaded hw-slab
  auto gemm2_mma = [&](int ks, const bf16x8* b2) {
    const int kg = ks * 4 + quad;
    bf16x8 a2[2];
    #pragma unroll
    for (int r = 0; r < 2; ++r)
      a2[r] = *(const bf16x8*)(smem + 49152 + (kg * 64 + wr * 32 + r * 16 + l16) * 16);
    #pragma unroll
    for (int r = 0; r < 2; ++r)
      #pragma unroll
      for (int c = 0; c < 4; ++c)
        acc_out[r][c] = __builtin_amdgcn_mfma_f32_16x16x32_bf16(a2[r], b2[c], acc_out[r][c], 0, 0, 0);
  };

  stage_sgrp(0, 0, 0);
  __syncthreads();   // prologue full drain: X + Sbuf0 + x2v all resident; vmcnt carried = 0

  #pragma unroll 1
  for (int mt = 0; mt < 8; ++mt) {
    const int mtg  = half * 8 + mt;
    const int mtg2 = mtg - (mt > 0);   // safe slab addr at mt==0 (values unused)

    // s2v for this mt's epilogue (4 vmem loads, counted in grp-0's wait)
    float s2v[4];
    #pragma unroll
    for (int c = 0; c < 4; ++c)
      s2v[c] = s2g[mtg * 128 + wc * 64 + c * 16 + l16];

    #pragma unroll
    for (int grp = 0; grp < 8; ++grp) {
      // barrier_A: all waves done reading buf[(grp+1)&1] (compute(grp-1));
      // at grp==0 the epilogue/prologue barrier already provides this.
      if (grp > 0) __builtin_amdgcn_s_barrier();

      bf16x8 b2[4];
      if ((grp & 1) == 0) g2_load(mtg2, grp >> 1, b2);

      if (grp < 7)      stage_sgrp(mt, grp + 1, (grp + 1) & 1);
      else if (mt < 7)  stage_sgrp(mt + 1, 0, 0);

      // own-wave counted wait for stage(grp), then barrier_B => all waves' stage(grp) landed
      if (grp == 0)            WAITVM(10);
      else if (grp == 7)       { if (mt < 7) { WAITVM(2); } else { WAITVM(0); } }
      else if ((grp & 1) == 0) WAITVM(6);
      else                     WAITVM(2);
      __builtin_amdgcn_s_barrier();

      compute_kc(grp * 2,     0, grp & 1);
      compute_kc(grp * 2 + 1, 1, grp & 1);
      if (mt > 0 && (grp & 1) == 0) gemm2_mma(grp >> 1, b2);
    }

    // ---- epilogue: t = acc + x2g + s2g = gamma*log2e*sqdist ; k = min(exp2(-t),1) -> bf16 Ks ----
    {
      #pragma unroll
      for (int r = 0; r < 2; ++r)
        #pragma unroll
        for (int c = 0; c < 4; ++c) {
          const int cl = wc * 64 + c * 16 + l16;     // m-col 0..127
          char* kbase = smem + 49152 + (cl >> 3) * 1024 + (cl & 7) * 2;
          #pragma unroll
          for (int i = 0; i < 4; ++i) {
            const int row = wr * 32 + r * 16 + quad * 4 + i;
            const float t = acc_xs[r][c][i] + x2v[r][i] + s2v[c];
            float kv = __builtin_amdgcn_exp2f(-t);
            kv = fminf(kv, 1.0f);
            *(u16*)(kbase + row * 16) = (u16)(__float_as_uint(kv) >> 16);
            acc_xs[r][c][i] = 0.0f;
          }
        }
    }
    // lgkm-only barrier: orders Ks ds_writes before next mt's gemm2 reads, WITHOUT
    // draining the in-flight stage(mt+1,0) prefetch.
    asm volatile("s_waitcnt lgkmcnt(0)" ::: "memory");
    __builtin_amdgcn_sched_barrier(0);
    __builtin_amdgcn_s_barrier();
  }

  // ---- drained GEMM2 for the last mtile ----
  #pragma unroll
  for (int ks = 0; ks < 4; ++ks) {
    bf16x8 b2[4];
    g2_load(half * 8 + 7, ks, b2);
    gemm2_mma(ks, b2);
  }

  // ---- final: atomic-accumulate scale*acc (+ bias/shift once, by half==0 blocks) ----
  float addv[4];
  #pragma unroll
  for (int c = 0; c < 4; ++c) {
    const int col = wc * 64 + c * 16 + l16;
    addv[c] = (half == 0) ? (vscale * head_b[col] + vshift) : 0.0f;
  }
  #pragma unroll
  for (int r = 0; r < 2; ++r)
    #pragma unroll
    for (int c = 0; c < 4; ++c) {
      const int col = wc * 64 + c * 16 + l16;
      #pragma unroll
      for (int i = 0; i < 4; ++i) {
        const int row = b0 + wr * 32 + r * 16 + quad * 4 + i;
        atomicAdd(&out[(size_t)row * NOUT + col], vscale * acc_out[r][c][i] + addv[c]);
      }
    }
}

// ---------- launch ----------
extern "C" void kernel_launch(void* const* d_in, const int* in_sizes, int n_in,
                              void* d_out, int out_size, void* d_ws, size_t ws_size,
                              hipStream_t stream) {
  const float* x       = (const float*)d_in[0];
  const float* support = (const float*)d_in[1];
  const float* gamma   = (const float*)d_in[2];
  const float* head_w  = (const float*)d_in[3];
  const float* head_b  = (const float*)d_in[4];
  const float* scale   = (const float*)d_in[5];
  const float* shift   = (const float*)d_in[6];
  float* out = (float*)d_out;

  char* w = (char*)d_ws;
  u8*    x_ws  = (u8*)(w);                        //  8,388,608 B
  u8*    s_ws  = (u8*)(w + 8388608);              //  2,097,152 B
  u16*   hw_ws = (u16*)(w + 10485760);            //  1,048,576 B
  float* x2g   = (float*)(w + 11534336);          //     65,536 B
  float* s2g   = (float*)(w + 11599872);          //     16,384 B

  prep_all<<<736, 256, 0, stream>>>(x, support, head_w, gamma,
                                    x_ws, s_ws, hw_ws, x2g, s2g, out);
  rbf_fused<<<1024, 256, 0, stream>>>(x_ws, s_ws, hw_ws, x2g, s2g,
                                      head_b, scale, shift, out);
}

// Round 2
// 176.248 us; speedup vs baseline: 1.0937x; 1.0937x over previous
//
#include <hip/hip_runtime.h>

typedef unsigned int u32;
typedef unsigned short u16;
typedef unsigned char u8;
typedef __attribute__((ext_vector_type(8))) __bf16 bf16x8;
typedef __attribute__((ext_vector_type(4))) float f32x4;

#define NB 16384
#define NM 4096
#define ND 512
#define NOUT 128
#define L2E 1.44269504088896340736f

// ws layout: x_ws fp8 [rb(256)][kg64(64)][row(64)][8B]   (8 MB)
//            s_ws fp8 [mb(32)][kg64(64)][m(128)][8B]     (2 MB, pre-scaled by -2*gamma*log2e)
//            hw_ws bf16 [slab=(mb*16+kg)][o(128)][8]     (1 MB)
// x2g[16384] = gamma*log2e*||x||^2 ; s2g[4096] = gamma*log2e*||s||^2  (fp32-exact)

// combined counted wait + scheduling fence (rule #18)
#define WAITLG(N) do { asm volatile("s_waitcnt vmcnt(" #N ") lgkmcnt(0)" ::: "memory"); \
                       __builtin_amdgcn_sched_barrier(0); } while (0)
#define SB0() __builtin_amdgcn_sched_barrier(0)

// ---------- helpers ----------
__device__ __forceinline__ u16 f2bf(float f) {
  u32 u = __float_as_uint(f);
  u += 0x7FFFu + ((u >> 16) & 1u);   // RNE
  return (u16)(u >> 16);
}

// manual fp32 -> e4m3fn (RNE, flush |v|<2^-6 to 0; |v| <= ~15 here so no sat needed)
__device__ __forceinline__ u8 f2fp8(float f) {
  u32 u = __float_as_uint(f);
  u32 s = (u >> 24) & 0x80u;
  u32 au = u & 0x7FFFFFFFu;
  if (au < 0x3C800000u) return (u8)s;          // below min normal -> 0
  au += 0x000FFFFFu + ((au >> 20) & 1u);       // RNE to 3 mantissa bits
  u32 e = (au >> 23) - 120u;                   // rebias 127 -> 7
  u32 m = (au >> 20) & 7u;
  return (u8)(s | (e << 3) | m);
}

__device__ __forceinline__ void stage16(const void* g, void* l) {
  __builtin_amdgcn_global_load_lds((__attribute__((address_space(1))) void*)g,
                                   (__attribute__((address_space(3))) void*)l,
                                   16, 0, 0);
}

__device__ __forceinline__ uint4 pack8bf(float4 v0, float4 v1) {
  uint4 pk;
  pk.x = (u32)f2bf(v0.x) | ((u32)f2bf(v0.y) << 16);
  pk.y = (u32)f2bf(v0.z) | ((u32)f2bf(v0.w) << 16);
  pk.z = (u32)f2bf(v1.x) | ((u32)f2bf(v1.y) << 16);
  pk.w = (u32)f2bf(v1.z) | ((u32)f2bf(v1.w) << 16);
  return pk;
}

__device__ __forceinline__ uint2 pack8f8(float4 v0, float4 v1) {
  uint2 pk;
  pk.x = (u32)f2fp8(v0.x) | ((u32)f2fp8(v0.y) << 8) |
         ((u32)f2fp8(v0.z) << 16) | ((u32)f2fp8(v0.w) << 24);
  pk.y = (u32)f2fp8(v1.x) | ((u32)f2fp8(v1.y) << 8) |
         ((u32)f2fp8(v1.z) << 16) | ((u32)f2fp8(v1.w) << 24);
  return pk;
}

// ---------- merged prep ----------
// blocks [0,512): x tiles (fp8)   [512,640): support tiles (fp8, scaled)
// [640,672): head_w (bf16)        [672,736): zero d_out (64 blocks x 128 KB)
__global__ __launch_bounds__(256) void prep_all(const float* __restrict__ x,
                                                const float* __restrict__ s,
                                                const float* __restrict__ hw,
                                                const float* __restrict__ gamma_p,
                                                u8*  __restrict__ x_ws,
                                                u8*  __restrict__ s_ws,
                                                u16* __restrict__ hw_ws,
                                                float* __restrict__ x2g,
                                                float* __restrict__ s2g,
                                                float* __restrict__ out) {
  __shared__ uint2 t8[2048];       // 16 KB (x/s transpose, XOR-swizzled)
  __shared__ uint4 t16[2048];      // 32 KB (hw transpose)
  const int tid = threadIdx.x, bid = blockIdx.x;
  const int lane = tid & 63, w = tid >> 6;

  if (bid < 640) {
    const bool isx = bid < 512;
    const int blk = isx ? bid : (bid - 512);
    const float* src_m = isx ? x : s;
    u8*    dst_ws = isx ? x_ws : s_ws;
    float* sq_out = isx ? x2g : s2g;
    const float gl   = gamma_p[0] * L2E;
    const float cmul = isx ? 1.0f : (-2.0f * gl);
    const int big  = isx ? (blk >> 1) : (blk >> 2);
    const int roff = isx ? ((blk & 1) * 32) : ((blk & 3) * 32);
    const int rows = isx ? 64 : 128;

    #pragma unroll
    for (int p = 0; p < 8; ++p) {
      const int row = p * 4 + w;                      // local row 0..31
      const float* src = src_m + (size_t)(blk * 32 + row) * ND + lane * 8;
      float4 v0 = *(const float4*)src;
      float4 v1 = *(const float4*)(src + 4);
      float ss = v0.x*v0.x + v0.y*v0.y + v0.z*v0.z + v0.w*v0.w
               + v1.x*v1.x + v1.y*v1.y + v1.z*v1.z + v1.w*v1.w;
      #pragma unroll
      for (int off = 32; off > 0; off >>= 1) ss += __shfl_down(ss, off);
      if (lane == 0) sq_out[blk * 32 + row] = gl * ss;
      v0.x *= cmul; v0.y *= cmul; v0.z *= cmul; v0.w *= cmul;
      v1.x *= cmul; v1.y *= cmul; v1.z *= cmul; v1.w *= cmul;
      t8[lane * 32 + ((row + lane) & 31)] = pack8f8(v0, v1);   // kg = lane
    }
    __syncthreads();
    #pragma unroll
    for (int p = 0; p < 8; ++p) {
      const int kg = p * 8 + (tid >> 5);
      const int row = tid & 31;
      uint2 pk = t8[kg * 32 + ((row + kg) & 31)];
      *(uint2*)&dst_ws[(((size_t)(big * 64 + kg)) * rows + roff + row) * 8] = pk;
    }
  } else if (bid < 672) {
    // ---- head_w: m-chunk of 128 (bf16) ----
    const int blk = bid - 640;
    #pragma unroll
    for (int p = 0; p < 8; ++p) {
      const int o = p * 16 + (tid >> 4);
      const int kg = tid & 15;
      const float* src = hw + (size_t)o * NM + blk * 128 + kg * 8;
      float4 v0 = *(const float4*)src;
      float4 v1 = *(const float4*)(src + 4);
      t16[o * 16 + ((kg + o) & 15)] = pack8bf(v0, v1);
    }
    __syncthreads();
    #pragma unroll
    for (int it = 0; it < 8; ++it) {
      const int kg = it * 2 + (tid >> 7);
      const int o = tid & 127;
      uint4 pk = t16[o * 16 + ((kg + o) & 15)];
      *(uint4*)&hw_ws[(((size_t)(blk * 16 + kg)) * 128 + o) * 8] = pk;
    }
  } else {
    // ---- zero d_out: 64 blocks x 128 KB ----
    float4* o4 = (float4*)out;
    const float4 z = {0.f, 0.f, 0.f, 0.f};
    size_t base = (size_t)(bid - 672) * 8192 + tid;
    #pragma unroll 8
    for (int i = 0; i < 32; ++i) o4[base + (size_t)i * 256] = z;
  }
}

// ---------- main fused kernel ----------
// grid 1024: xcd = bid&7, half = xcd>>1 (M quarter), rb = (bid>>3)*2 + (xcd&1).
// block 256 = 4 waves; wave tile 32x64 (2x4 16x16x32 frags).
// LDS 80 KB DYNAMIC: X fp8 32K @0 (resident); Sbuf RING 4x8K @32768 (depth-3 prefetch);
// Ks bf16 16K @65536.  2 blocks/CU x 80K = 160K = full LDS pool.
//
// R2 schedule (m201 pattern, ONE barrier/grp): flat t = mt*8+grp, buf = t&3:
//   [frag ds_reads(t) from buf | a2 Ks reads | b2(t+2) glb loads | s2v@grp0]
//   SB(0); stage(t+3) -> buf (t+3)&3; s_waitcnt vmcnt(K) lgkmcnt(0); SB(0);
//   s_barrier; SB(0); setprio(1); MFMA(t) register-only (+gemm2 w/ b2 from t-2); setprio(0)
// Post-barrier region is pure-register -> sibling waves' pre-barrier LDS/issue bursts
// overlap MFMA. lgkm drains PRE-barrier (ring hazard: buf (t+3)&3 re-written one barrier
// after its last read). K table (exact, region order pinned by SB0):
//   mt<7: {12,12,8,8,8,8,8,8}[grp]; mt==7: {12,12,8,8,8,6,0,0}.
// b2 double-buffered (b2a/b2b), loaded 2 iters ahead => older than wait target; compiler's
// own b2-dependency wait is provably looser than in-flight stage count (no forced drain).
__global__ __launch_bounds__(256, 2)
void rbf_fused(const u8* __restrict__ x_ws, const u8* __restrict__ s_ws,
               const u16* __restrict__ hw_ws, const float* __restrict__ x2g,
               const float* __restrict__ s2g, const float* __restrict__ head_b,
               const float* __restrict__ scale_p, const float* __restrict__ shift_p,
               float* __restrict__ out)
{
  extern __shared__ __align__(16) char smem[];   // 80 KB dynamic

  const int tid  = threadIdx.x;
  const int w    = tid >> 6;
  const int lane = tid & 63;
  const int quad = lane >> 4;
  const int l16  = lane & 15;
  const int wr   = w & 1;    // row half (32 rows)
  const int wc   = w >> 1;   // m / out-col half (64)
  const int xcd  = blockIdx.x & 7;
  const int rb   = (blockIdx.x >> 3) * 2 + (xcd & 1);
  const int half = xcd >> 1;
  const int b0   = rb * 64;

  const float vscale = scale_p[0];
  const float vshift = shift_p[0];

  const u8* xsrc = x_ws + (size_t)rb * 32768;
  const u8* ssrc = s_ws + (size_t)(half * 8) * 65536;

  auto stage_grp = [&](int mt_s, int grp_s) {
    const u8* sp = ssrc + (size_t)mt_s * 65536 + grp_s * 8192;
    char* dp = smem + 32768 + (grp_s & 3) * 8192;
    stage16(sp + tid * 16, dp + tid * 16);
    stage16(sp + 4096 + tid * 16, dp + 4096 + tid * 16);
  };

  // ---- prologue: X slice (32 KB) + S(0),S(1),S(2); issue order pinned ----
  #pragma unroll
  for (int i = 0; i < 8; ++i)
    stage16(xsrc + i * 4096 + tid * 16, smem + i * 4096 + tid * 16);
  SB0();

  f32x4 x2v[2];
  #pragma unroll
  for (int r = 0; r < 2; ++r)
    x2v[r] = *(const f32x4*)&x2g[b0 + wr * 32 + r * 16 + quad * 4];

  stage_grp(0, 0); SB0();
  stage_grp(0, 1); SB0();
  stage_grp(0, 2);
  asm volatile("s_waitcnt vmcnt(4)" ::: "memory");   // X + S(0) done; S(1),S(2) in flight
  SB0();
  __builtin_amdgcn_s_barrier();
  SB0();

  const f32x4 zf = {0.f, 0.f, 0.f, 0.f};
  f32x4 acc_xs[2][4];
  f32x4 acc_out[2][4];
  #pragma unroll
  for (int r = 0; r < 2; ++r)
    #pragma unroll
    for (int c = 0; c < 4; ++c) { acc_xs[r][c] = zf; acc_out[r][c] = zf; }

  bf16x8 b2a[4], b2b[4];       // gemm2 B double-buffer (loaded 2 iters ahead)

  #pragma unroll 1
  for (int mt = 0; mt < 8; ++mt) {
    const int mtg = half * 8 + mt;
    float s2v[4];

    #pragma unroll
    for (int grp = 0; grp < 8; ++grp) {
      // ---- pre-barrier region ----
      if (grp == 0) {
        #pragma unroll
        for (int c = 0; c < 4; ++c)
          s2v[c] = s2g[mtg * 128 + wc * 64 + c * 16 + l16];
      }

      // fragment ds_reads for this grp (both kc) from Sbuf[grp&3] + resident X
      long long a[2][2], b[2][4];
      #pragma unroll
      for (int k2 = 0; k2 < 2; ++k2) {
        const int kc = grp * 2 + k2;
        #pragma unroll
        for (int r = 0; r < 2; ++r)
          a[k2][r] = *(const long long*)(smem + ((kc * 4 + quad) * 64 + wr * 32 + r * 16 + l16) * 8);
        #pragma unroll
        for (int c = 0; c < 4; ++c)
          b[k2][c] = *(const long long*)(smem + 32768 + (grp & 3) * 8192 +
                                         ((k2 * 4 + quad) * 128 + wc * 64 + c * 16 + l16) * 8);
      }

      // Ks reads for this grp's folded gemm2 (stable within mt)
      bf16x8 a2[2];
      if (mt > 0 && (grp & 1) == 0) {
        const int kg = (grp >> 1) * 4 + quad;
        #pragma unroll
        for (int r = 0; r < 2; ++r)
          a2[r] = *(const bf16x8*)(smem + 65536 + (kg * 64 + wr * 32 + r * 16 + l16) * 16);
      }

      // b2 loads for consumer iter t+2 (skip only at t==62)
      if ((grp & 1) == 0 && !(mt == 7 && grp == 6)) {
        const int gc = (grp + 2) & 7;
        const int mc = mt + (grp == 6);
        int slab_mt = half * 8 + mc - 1; if (slab_mt < 0) slab_mt = 0;  // dummy at mt0 head
        const int kgc = (gc >> 1) * 4 + quad;
        const size_t sb = (size_t)(slab_mt * 16 + kgc);
        #pragma unroll
        for (int c = 0; c < 4; ++c) {
          bf16x8 v = *(const bf16x8*)(hw_ws + (sb * 128 + wc * 64 + c * 16 + l16) * 8);
          if (((grp >> 1) & 1) == 0) b2a[c] = v; else b2b[c] = v;
        }
      }

      SB0();   // pin: all region vmem above, stage below (keeps wait-target last in queue)

      // stage flat t+3
      if (grp <= 4)      stage_grp(mt, grp + 3);
      else if (mt < 7)   stage_grp(mt + 1, grp - 5);

      // counted wait: target = stage(t+1) done (+ own ds_reads drained pre-barrier)
      if (grp == 0 || grp == 1)  WAITLG(12);
      else if (grp <= 4)         WAITLG(8);
      else if (grp == 5)         { if (mt < 7) WAITLG(8); else WAITLG(6); }
      else                       { if (mt < 7) WAITLG(8); else WAITLG(0); }

      __builtin_amdgcn_s_barrier();
      SB0();

      // ---- post-barrier region: pure-register MFMA ----
      __builtin_amdgcn_s_setprio(1);
      #pragma unroll
      for (int k2 = 0; k2 < 2; ++k2)
        #pragma unroll
        for (int r = 0; r < 2; ++r)
          #pragma unroll
          for (int c = 0; c < 4; ++c)
            acc_xs[r][c] = __builtin_amdgcn_mfma_f32_16x16x32_fp8_fp8(a[k2][r], b[k2][c],
                                                                      acc_xs[r][c], 0, 0, 0);
      if (mt > 0 && (grp & 1) == 0) {
        #pragma unroll
        for (int r = 0; r < 2; ++r)
          #pragma unroll
          for (int c = 0; c < 4; ++c) {
            bf16x8 bb = ((((grp >> 1) + 1) & 1) == 0) ? b2a[c] : b2b[c];
            acc_out[r][c] = __builtin_amdgcn_mfma_f32_16x16x32_bf16(a2[r], bb,
                                                                    acc_out[r][c], 0, 0, 0);
          }
      }
      __builtin_amdgcn_s_setprio(0);
    }

    // ---- epilogue: t = acc + x2g + s2g ; k = min(exp2(-t),1) -> bf16 Ks ----
    {
      #pragma unroll
      for (int r = 0; r < 2; ++r)
        #pragma unroll
        for (int c = 0; c < 4; ++c) {
          const int cl = wc * 64 + c * 16 + l16;     // m-col 0..127
          char* kbase = smem + 65536 + (cl >> 3) * 1024 + (cl & 7) * 2;
          #pragma unroll
          for (int i = 0; i < 4; ++i) {
            const int row = wr * 32 + r * 16 + quad * 4 + i;
            const float t = acc_xs[r][c][i] + x2v[r][i] + s2v[c];
            float kv = __builtin_amdgcn_exp2f(-t);
            kv = fminf(kv, 1.0f);
            *(u16*)(kbase + row * 16) = (u16)(__float_as_uint(kv) >> 16);
            acc_xs[r][c][i] = 0.0f;
          }
        }
    }
    // lgkm-only barrier: orders Ks writes before next mt's gemm2 reads, keeps stages in flight
    asm volatile("s_waitcnt lgkmcnt(0)" ::: "memory");
    SB0();
    __builtin_amdgcn_s_barrier();
    SB0();
  }

  // ---- drained GEMM2 for the last mtile ----
  #pragma unroll
  for (int ks = 0; ks < 4; ++ks) {
    const int kg = ks * 4 + quad;
    const size_t slab = (size_t)((half * 8 + 7) * 16 + kg);
    bf16x8 b2[4], a2[2];
    #pragma unroll
    for (int c = 0; c < 4; ++c)
      b2[c] = *(const bf16x8*)(hw_ws + (slab * 128 + wc * 64 + c * 16 + l16) * 8);
    #pragma unroll
    for (int r = 0; r < 2; ++r)
      a2[r] = *(const bf16x8*)(smem + 65536 + (kg * 64 + wr * 32 + r * 16 + l16) * 16);
    #pragma unroll
    for (int r = 0; r < 2; ++r)
      #pragma unroll
      for (int c = 0; c < 4; ++c)
        acc_out[r][c] = __builtin_amdgcn_mfma_f32_16x16x32_bf16(a2[r], b2[c], acc_out[r][c], 0, 0, 0);
  }

  // ---- final: atomic-accumulate scale*acc (+ bias/shift once, by half==0 blocks) ----
  float addv[4];
  #pragma unroll
  for (int c = 0; c < 4; ++c) {
    const int col = wc * 64 + c * 16 + l16;
    addv[c] = (half == 0) ? (vscale * head_b[col] + vshift) : 0.0f;
  }
  #pragma unroll
  for (int r = 0; r < 2; ++r)
    #pragma unroll
    for (int c = 0; c < 4; ++c) {
      const int col = wc * 64 + c * 16 + l16;
      #pragma unroll
      for (int i = 0; i < 4; ++i) {
        const int row = b0 + wr * 32 + r * 16 + quad * 4 + i;
        atomicAdd(&out[(size_t)row * NOUT + col], vscale * acc_out[r][c][i] + addv[c]);
      }
    }
}

// ---------- launch ----------
extern "C" void kernel_launch(void* const* d_in, const int* in_sizes, int n_in,
                              void* d_out, int out_size, void* d_ws, size_t ws_size,
                              hipStream_t stream) {
  const float* x       = (const float*)d_in[0];
  const float* support = (const float*)d_in[1];
  const float* gamma   = (const float*)d_in[2];
  const float* head_w  = (const float*)d_in[3];
  const float* head_b  = (const float*)d_in[4];
  const float* scale   = (const float*)d_in[5];
  const float* shift   = (const float*)d_in[6];
  float* out = (float*)d_out;

  char* w = (char*)d_ws;
  u8*    x_ws  = (u8*)(w);                        //  8,388,608 B
  u8*    s_ws  = (u8*)(w + 8388608);              //  2,097,152 B
  u16*   hw_ws = (u16*)(w + 10485760);            //  1,048,576 B
  float* x2g   = (float*)(w + 11534336);          //     65,536 B
  float* s2g   = (float*)(w + 11599872);          //     16,384 B

  static bool lds_init = false;
  if (!lds_init) {
    hipFuncSetAttribute(reinterpret_cast<const void*>(rbf_fused),
                        hipFuncAttributeMaxDynamicSharedMemorySize, 81920);
    lds_init = true;
  }

  prep_all<<<736, 256, 0, stream>>>(x, support, head_w, gamma,
                                    x_ws, s_ws, hw_ws, x2g, s2g, out);
  rbf_fused<<<1024, 256, 81920, stream>>>(x_ws, s_ws, hw_ws, x2g, s2g,
                                          head_b, scale, shift, out);
}